// Round 1
// 65.183 us; speedup vs baseline: 1.0100x; 1.0100x over previous
//
#include <hip/hip_runtime.h>

// Fixed problem constants: H=W=128, B=16, KS=21, centers at 4k+2 (32x32 grid),
// SDP2=25 -> weight exp(-d^2/50). Output (16,16384,1) f32.
//
// Round 4 changes vs round 3 (LDS-read-bound per pipe model):
//  - Vertical-pair processing: one thread computes pixels (r, r+1), sharing
//    the alpha window reads via a 12-row x 20-col UNION window (superset of
//    both pixels' 11x16 windows -> accuracy can only improve; weights are the
//    same exact multiplicative recurrence). LDS b128 per pixel: 44 -> 33.
//  - Row-pass temp packed as float4 (both rows per slot): def col-pass reads
//    6 x b128 per pair instead of 12 x b64.
//  - sA padding cols 32..35 zeroed (20-wide reads touch them; weights beyond
//    col 31 multiply zero alpha, matching the reference domain).
//  - Grid 1024 x 128: 4 blocks/CU, 8 waves/CU, 2x ILP per thread.

constexpr float K_RATIO = 0.52729243f;  // exp(-0.64)

__global__ __launch_bounds__(128, 2) void kbpa_kernel(
    const float* __restrict__ betas,   // (16,32,32,2)
    const float* __restrict__ alphas,  // (32,32)
    const float* __restrict__ gker,    // (21,21)
    float* __restrict__ out)           // (16*16384,)
{
    __shared__ float  gp[32];          // zero-padded g row: g[j] at gp[j+4]
    __shared__ float2 sB[7][32];       // beta rows trA..trA+6 (zero if OOB)
    __shared__ float  sA[32 * 36];     // alphas, row stride 36; cols 32..35 = 0
    __shared__ float4 sT4[44];         // row-pass tmp: .xy = row r0, .zw = row r0+1

    const int t   = threadIdx.x;
    const int b   = blockIdx.x >> 6;          // 16 batches
    const int r0  = (blockIdx.x & 63) << 1;   // pixel-row pair r0, r0+1
    const int trA = (r0 - 7) >> 2;            // first staged beta row

    // ---- stage A: all staging, one barrier ----
    if (t < 88) ((float2*)sT4)[t] = make_float2(0.0f, 0.0f);
    if (t < 32) gp[t] = (t >= 4 && t <= 24) ? gker[210 + t - 4] : 0.0f;
    {   // alphas -> 32x36 padded, 2 float4 per thread
        const int row = t >> 2, col = (t & 3) << 3;
        *(float4*)(sA + row * 36 + col) =
            *(const float4*)(alphas + (row << 5) + col);
        *(float4*)(sA + row * 36 + col + 4) =
            *(const float4*)(alphas + (row << 5) + col + 4);
    }
    if (t < 32)  // zero the pad: 20-wide window reads may touch cols 32..35
        *(float4*)(sA + t * 36 + 32) = make_float4(0.0f, 0.0f, 0.0f, 0.0f);
    for (int s = t; s < 224; s += 128) {  // 7 beta rows x 32 cols, zero if OOB
        const int k = s >> 5, tc = s & 31;
        const int tr = trA + k;
        float2 v = make_float2(0.0f, 0.0f);
        if ((unsigned)tr < 32u)
            v = ((const float2*)betas)[(b << 10) + (tr << 5) + tc];
        sB[k][tc] = v;
    }
    __syncthreads();

    // ---- stage B: separable deformation row pass (both rows, 64 threads) ----
    if (t < 64) {
        const int ty = t >> 5, tc = t & 31;   // ty = row-in-pair
        const int r   = r0 + ty;
        const int tr0 = (r - 7) >> 2;
        const int k0  = tr0 - trA;            // 0 or 1
        float ax = 0.0f, ay = 0.0f;
#pragma unroll
        for (int k = 0; k < 6; ++k) {
            const float  w = gp[4 * (tr0 + k) - r + 14];  // pad=0 outside
            const float2 v = sB[k0 + k][tc];
            ax = fmaf(w, v.x, ax);
            ay = fmaf(w, v.y, ay);
        }
        *(float2*)((float*)&sT4[tc + 4] + (ty << 1)) = make_float2(ax, ay);
    }
    __syncthreads();

    // ---- stage C: one vertical pixel pair per thread ----
    const int c = t;

    // deformation col pass: 6 taps, both rows per b128 read
    const int tc0 = (c - 7) >> 2;
    const int dc0 = 4 * tc0 - c + 10;          // in [0,3]
    float d0A = 0.0f, d1A = 0.0f, d0B = 0.0f, d1B = 0.0f;
#pragma unroll
    for (int j = 0; j < 6; ++j) {
        const float  w = gp[dc0 + 4 * j + 4];
        const float4 v = sT4[tc0 + j + 4];     // idx in [2,39], pad=0
        d0A = fmaf(w, v.x, d0A); d1A = fmaf(w, v.y, d1A);
        d0B = fmaf(w, v.z, d0B); d1B = fmaf(w, v.w, d1B);
    }

    const float pxA = (float)r0 - d0A,       pyA = (float)c - d1A;
    const float pxB = (float)(r0 + 1) - d0B, pyB = (float)c - d1B;

    // union window: 12 rows x 20 cols covering both pixels' 11x16 windows
    const int m0rA = min(max(__float2int_rn((pxA - 2.0f) * 0.25f) - 5, 0), 21);
    const int m0rB = min(max(__float2int_rn((pxB - 2.0f) * 0.25f) - 5, 0), 21);
    const int m0r  = min(min(m0rA, m0rB), 20);            // +11 <= 31
    const int m0cA = min(max((__float2int_rn((pyA - 2.0f) * 0.25f) - 5) & ~3, 0), 16);
    const int m0cB = min(max((__float2int_rn((pyB - 2.0f) * 0.25f) - 5) & ~3, 0), 16);
    const int m0c  = min(m0cA, m0cB);                     // +19 <= 35 (pad=0)

    // col weights Ec[j] = exp(-d_j^2/50), d_j = d0 - 4j, exact recurrence
    float EcA[20], EcB[20];
    {
        const float d0 = pyA - (float)(4 * m0c + 2);
        float E = __expf(-d0 * d0 * 0.02f);
        float u = __expf(0.16f * d0 - 0.32f);
        EcA[0] = E;
#pragma unroll
        for (int j = 1; j < 20; ++j) { E *= u; u *= K_RATIO; EcA[j] = E; }
    }
    {
        const float d0 = pyB - (float)(4 * m0c + 2);
        float E = __expf(-d0 * d0 * 0.02f);
        float u = __expf(0.16f * d0 - 0.32f);
        EcB[0] = E;
#pragma unroll
        for (int j = 1; j < 20; ++j) { E *= u; u *= K_RATIO; EcB[j] = E; }
    }

    // row weights by the same recurrence, fused into the accumulation loop
    const float drA = pxA - (float)(4 * m0r + 2);
    float erA = __expf(-drA * drA * 0.02f);
    float urA = __expf(0.16f * drA - 0.32f);
    const float drB = pxB - (float)(4 * m0r + 2);
    float erB = __expf(-drB * drB * 0.02f);
    float urB = __expf(0.16f * drB - 0.32f);

    float accA = 0.0f, accB = 0.0f;
    const float* aBase = sA + m0r * 36 + m0c;   // 16B-aligned (36*4B, m0c%4==0)
#pragma unroll
    for (int i = 0; i < 12; ++i) {
        float sAcc = 0.0f, sBcc = 0.0f;
#pragma unroll
        for (int q = 0; q < 5; ++q) {
            const float4 a = *(const float4*)(aBase + i * 36 + 4 * q);
            sAcc = fmaf(a.x, EcA[4 * q + 0], sAcc);
            sBcc = fmaf(a.x, EcB[4 * q + 0], sBcc);
            sAcc = fmaf(a.y, EcA[4 * q + 1], sAcc);
            sBcc = fmaf(a.y, EcB[4 * q + 1], sBcc);
            sAcc = fmaf(a.z, EcA[4 * q + 2], sAcc);
            sBcc = fmaf(a.z, EcB[4 * q + 2], sBcc);
            sAcc = fmaf(a.w, EcA[4 * q + 3], sAcc);
            sBcc = fmaf(a.w, EcB[4 * q + 3], sBcc);
        }
        accA = fmaf(erA, sAcc, accA); erA *= urA; urA *= K_RATIO;
        accB = fmaf(erB, sBcc, accB); erB *= urB; urB *= K_RATIO;
    }

    float* o = out + (b << 14) + (r0 << 7) + c;
    o[0]   = accA;
    o[128] = accB;
}

extern "C" void kernel_launch(void* const* d_in, const int* in_sizes, int n_in,
                              void* d_out, int out_size, void* d_ws, size_t ws_size,
                              hipStream_t stream) {
    const float* betas  = (const float*)d_in[0];
    const float* alphas = (const float*)d_in[1];
    const float* gker   = (const float*)d_in[2];
    float* out = (float*)d_out;
    kbpa_kernel<<<1024, 128, 0, stream>>>(betas, alphas, gker, out);
}